// Round 1
// baseline (586.746 us; speedup 1.0000x reference)
//
#include <hip/hip_runtime.h>
#include <stdint.h>

// ---------------------------------------------------------------------------
// MaxSim InfoNCE on MI355X (gfx950)
//   image_tokens: [128, 196, 512] fp32   (d_in[0])
//   text_tokens : [128,  64, 512] fp32   (d_in[1])
//   out         : scalar fp32 loss
//
// Pipeline:
//   1) pack_text_k : fp32 -> bf16, [128*64, 512]
//   2) pack_image_k: fp32 -> bf16, padded to [128, 208, 512] (pad rows = 0)
//   3) maxsim_gemm_k: per (b1-pair, b2) WG: 128x208 tile, K=512, bf16 MFMA
//      16x16x32, global_load_lds(16B) staging with XOR chunk swizzle;
//      fused max-over-i (mask i>=196) + mean-over-t -> sim[128][128]
//   4) loss_k: symmetric diagonal cross-entropy -> out[0]
// ---------------------------------------------------------------------------

typedef __attribute__((ext_vector_type(8))) short s8v;   // 8 bf16 (4 VGPRs)
typedef __attribute__((ext_vector_type(4))) float f4v;   // 4 fp32 acc

#define BB 128
#define TT 64
#define II 196
#define IP 208          // padded image tokens per batch (13*16)
#define DD 512
#define BKK 32
#define KSTEPS (DD / BKK)   // 16

static __device__ __forceinline__ unsigned short f2bf(float f) {
  union { float f; unsigned u; } v; v.f = f;
  return (unsigned short)((v.u + 0x7FFFu + ((v.u >> 16) & 1u)) >> 16);  // RNE
}

static __device__ __forceinline__ void async16(const void* g, void* l) {
  __builtin_amdgcn_global_load_lds(
      (const __attribute__((address_space(1))) void*)g,
      (__attribute__((address_space(3))) void*)l, 16, 0, 0);
}

// ---- pack text: 128*64*512 fp32 -> bf16 (8 elems / thread) ----
__global__ void pack_text_k(const float* __restrict__ in, uint4* __restrict__ out) {
  int c = blockIdx.x * blockDim.x + threadIdx.x;     // chunk of 8 elements
  const float4* in4 = (const float4*)in;
  float4 a = in4[2 * c], b = in4[2 * c + 1];
  union { unsigned short s[8]; uint4 q; } u;
  u.s[0] = f2bf(a.x); u.s[1] = f2bf(a.y); u.s[2] = f2bf(a.z); u.s[3] = f2bf(a.w);
  u.s[4] = f2bf(b.x); u.s[5] = f2bf(b.y); u.s[6] = f2bf(b.z); u.s[7] = f2bf(b.w);
  out[c] = u.q;
}

// ---- pack image: [128,196,512] fp32 -> [128,208,512] bf16, pad rows zeroed ----
__global__ void pack_image_k(const float* __restrict__ in, uint4* __restrict__ out) {
  int c = blockIdx.x * blockDim.x + threadIdx.x;     // chunk of 8 output elems
  int e = c * 8;
  int k = e & (DD - 1);
  int tok = e >> 9;                                   // padded token index
  int b2 = tok / IP;
  int r = tok - b2 * IP;
  union { unsigned short s[8]; uint4 q; } u;
  if (r < II) {
    const float4* in4 = (const float4*)(in + ((size_t)(b2 * II + r) * DD + k));
    float4 a = in4[0], b = in4[1];
    u.s[0] = f2bf(a.x); u.s[1] = f2bf(a.y); u.s[2] = f2bf(a.z); u.s[3] = f2bf(a.w);
    u.s[4] = f2bf(b.x); u.s[5] = f2bf(b.y); u.s[6] = f2bf(b.z); u.s[7] = f2bf(b.w);
  } else {
    u.q = make_uint4(0u, 0u, 0u, 0u);
  }
  out[c] = u.q;
}

// ---- main GEMM + fused max/mean ----
// grid: (64 pairs, 128 b2), block: 256 threads (4 waves, 2x2 over M/N)
__global__ __launch_bounds__(256) void maxsim_gemm_k(
    const unsigned short* __restrict__ A,    // text bf16 [128*64, 512]
    const unsigned short* __restrict__ Bm,   // image bf16 [128*208, 512]
    float* __restrict__ sim)                 // [128,128] mean-of-max
{
  // LDS tiles: [row][BK=32 bf16] = 4 chunks of 16B per row, XOR-swizzled:
  // physical chunk p of row r holds logical chunk p ^ ((r>>1)&3)
  __shared__ __align__(16) unsigned short As[128 * BKK];   // 8 KiB
  __shared__ __align__(16) unsigned short Bs[IP * BKK];    // 13 KiB
  __shared__ float partial[2][128];

  const int pr  = blockIdx.x;       // text pair: b1 in {2pr, 2pr+1}
  const int b2  = blockIdx.y;
  const int tid = threadIdx.x;
  const int w = tid >> 6, l = tid & 63;
  const int m = l & 15, q = l >> 4;
  const int waveM = w >> 1;         // M half: rows waveM*64..+63
  const int waveN = w & 1;          // N half: tiles 0..6 / 7..12
  const int nt = 7 - waveN;         // 7 or 6 N tiles for this wave

  // ---- staging descriptors (chunk id -> global elem offset sans k0) ----
  // A: 512 chunks (128 rows x 4); B: 832 chunks (208 rows x 4)
  const int ca0 = tid, ca1 = tid + 256;
  const int cb0 = tid, cb1 = tid + 256, cb2 = tid + 512, cb3 = 768 + l;
#define AOFF(c) ((size_t)((pr * 128 + ((c) >> 2)) * DD + ((((c) & 3) ^ ((((c) >> 2) >> 1) & 3)) * 8)))
#define BOFF(c) ((size_t)((b2 * IP + ((c) >> 2)) * DD + ((((c) & 3) ^ ((((c) >> 2) >> 1) & 3)) * 8)))
  const unsigned short* gA0 = A + AOFF(ca0);
  const unsigned short* gA1 = A + AOFF(ca1);
  const unsigned short* gB0 = Bm + BOFF(cb0);
  const unsigned short* gB1 = Bm + BOFF(cb1);
  const unsigned short* gB2 = Bm + BOFF(cb2);
  const unsigned short* gB3 = Bm + BOFF(cb3);
  char* lA0 = (char*)As + ca0 * 16;
  char* lA1 = (char*)As + ca1 * 16;
  char* lB0 = (char*)Bs + cb0 * 16;
  char* lB1 = (char*)Bs + cb1 * 16;
  char* lB2 = (char*)Bs + cb2 * 16;
  char* lB3 = (char*)Bs + cb3 * 16;

  f4v acc[4][7];
#pragma unroll
  for (int mi = 0; mi < 4; ++mi)
#pragma unroll
    for (int nj = 0; nj < 7; ++nj)
      acc[mi][nj] = (f4v){0.f, 0.f, 0.f, 0.f};

  const int swz = q ^ ((m >> 1) & 3);   // logical chunk q -> physical chunk
  const s8v* Av = (const s8v*)As;
  const s8v* Bv = (const s8v*)Bs;

  for (int ks = 0; ks < KSTEPS; ++ks) {
    const int k0 = ks * BKK;
    async16(gA0 + k0, lA0);
    async16(gA1 + k0, lA1);
    async16(gB0 + k0, lB0);
    async16(gB1 + k0, lB1);
    async16(gB2 + k0, lB2);
    if (w == 0) async16(gB3 + k0, lB3);
    __syncthreads();   // drains vmcnt before barrier (compiler-inserted)

    s8v af[4];
#pragma unroll
    for (int mi = 0; mi < 4; ++mi)
      af[mi] = Av[(waveM * 64 + mi * 16 + m) * 4 + swz];
#pragma unroll
    for (int nj = 0; nj < 7; ++nj) {
      if (nj < nt) {
        s8v bf = Bv[(waveN * 112 + nj * 16 + m) * 4 + swz];
#pragma unroll
        for (int mi = 0; mi < 4; ++mi)
          acc[mi][nj] = __builtin_amdgcn_mfma_f32_16x16x32_bf16(af[mi], bf, acc[mi][nj], 0, 0, 0);
      }
    }
    __syncthreads();
  }

  // ---- epilogue: max over image cols (mask >=196), then mean over t ----
  // C/D layout (16x16x32): col = lane&15, row = (lane>>4)*4 + reg
  const float NEG = -3.0e38f;
#pragma unroll
  for (int mi = 0; mi < 4; ++mi) {
    float v0 = NEG, v1 = NEG, v2 = NEG, v3 = NEG;
#pragma unroll
    for (int nj = 0; nj < 7; ++nj) {
      if (nj < nt) {
        int col = waveN * 112 + nj * 16 + m;
        bool valid = col < II;
        v0 = fmaxf(v0, valid ? acc[mi][nj][0] : NEG);
        v1 = fmaxf(v1, valid ? acc[mi][nj][1] : NEG);
        v2 = fmaxf(v2, valid ? acc[mi][nj][2] : NEG);
        v3 = fmaxf(v3, valid ? acc[mi][nj][3] : NEG);
      }
    }
#pragma unroll
    for (int off = 1; off < 16; off <<= 1) {
      v0 = fmaxf(v0, __shfl_xor(v0, off));
      v1 = fmaxf(v1, __shfl_xor(v1, off));
      v2 = fmaxf(v2, __shfl_xor(v2, off));
      v3 = fmaxf(v3, __shfl_xor(v3, off));
    }
    if (m == 0) {
      int rowb = waveM * 64 + mi * 16 + q * 4;
      partial[waveN][rowb + 0] = v0;
      partial[waveN][rowb + 1] = v1;
      partial[waveN][rowb + 2] = v2;
      partial[waveN][rowb + 3] = v3;
    }
  }
  __syncthreads();

  if (tid < 128) {
    float v = fmaxf(partial[0][tid], partial[1][tid]);  // max over all 196 i
#pragma unroll
    for (int off = 1; off < 64; off <<= 1) v += __shfl_xor(v, off);
    if ((tid & 63) == 0) {
      int b1 = pr * 2 + (tid >> 6);
      sim[b1 * BB + b2] = v * (1.0f / 64.0f);           // mean over t
    }
  }
}

// ---- symmetric diagonal cross-entropy over the 128x128 sim matrix ----
__global__ void loss_k(const float* __restrict__ sim, float* __restrict__ out) {
  const int b = threadIdx.x;                 // 0..127
  const float sc = 1.0f / 0.07f;
  float rmax = -3.0e38f, cmax = -3.0e38f;
  for (int j = 0; j < BB; ++j) {
    rmax = fmaxf(rmax, sim[b * BB + j]);
    cmax = fmaxf(cmax, sim[j * BB + b]);
  }
  float rs = 0.f, cs = 0.f;
  for (int j = 0; j < BB; ++j) {
    rs += __expf((sim[b * BB + j] - rmax) * sc);
    cs += __expf((sim[j * BB + b] - cmax) * sc);
  }
  float d = sim[b * BB + b];
  float v = (rmax - d) * sc + __logf(rs) + (cmax - d) * sc + __logf(cs);
  __shared__ float red[2];
#pragma unroll
  for (int off = 1; off < 64; off <<= 1) v += __shfl_xor(v, off);
  if ((b & 63) == 0) red[b >> 6] = v;
  __syncthreads();
  if (b == 0) out[0] = (red[0] + red[1]) * 0.5f / 128.0f;
}

extern "C" void kernel_launch(void* const* d_in, const int* in_sizes, int n_in,
                              void* d_out, int out_size, void* d_ws, size_t ws_size,
                              hipStream_t stream) {
  const float* img = (const float*)d_in[0];  // [128,196,512]
  const float* txt = (const float*)d_in[1];  // [128,64,512]
  float* out = (float*)d_out;

  char* ws = (char*)d_ws;
  const size_t TXT_BF = (size_t)BB * TT * DD * 2;        // 8,388,608 B
  const size_t IMG_BF = (size_t)BB * IP * DD * 2;        // 27,262,976 B
  unsigned short* txtbf = (unsigned short*)ws;
  unsigned short* imgbf = (unsigned short*)(ws + TXT_BF);
  float* sim = (float*)(ws + TXT_BF + IMG_BF);           // 65,536 B

  // text: 128*64*512 / 8 = 524288 chunks
  pack_text_k<<<2048, 256, 0, stream>>>(txt, (uint4*)txtbf);
  // image padded: 128*208*512 / 8 = 1703936 chunks
  pack_image_k<<<6656, 256, 0, stream>>>(img, (uint4*)imgbf);
  // GEMM: 64 text-pairs x 128 image batches
  maxsim_gemm_k<<<dim3(64, 128), 256, 0, stream>>>(txtbf, imgbf, sim);
  // loss
  loss_k<<<1, 128, 0, stream>>>(sim, out);
}

// Round 2
// 322.640 us; speedup vs baseline: 1.8186x; 1.8186x over previous
//
#include <hip/hip_runtime.h>
#include <stdint.h>

// ---------------------------------------------------------------------------
// MaxSim InfoNCE on MI355X (gfx950)
//   image_tokens: [128, 196, 512] fp32   (d_in[0])
//   text_tokens : [128,  64, 512] fp32   (d_in[1])
//   out         : scalar fp32 loss
//
// R2: single-barrier double-buffered K-loop. Prefetch step k+1 into the
// other LDS buffer BEFORE computing step k, so the vmcnt(0) drain at the
// end-of-step barrier is hidden behind the MFMA block. One barrier/step.
// ---------------------------------------------------------------------------

typedef __attribute__((ext_vector_type(8))) short s8v;   // 8 bf16 (4 VGPRs)
typedef __attribute__((ext_vector_type(4))) float f4v;   // 4 fp32 acc

#define BB 128
#define TT 64
#define II 196
#define IP 208          // padded image tokens per batch (13*16)
#define DD 512
#define BKK 32
#define KSTEPS (DD / BKK)   // 16

static __device__ __forceinline__ unsigned short f2bf(float f) {
  union { float f; unsigned u; } v; v.f = f;
  return (unsigned short)((v.u + 0x7FFFu + ((v.u >> 16) & 1u)) >> 16);  // RNE
}

static __device__ __forceinline__ void async16(const void* g, void* l) {
  __builtin_amdgcn_global_load_lds(
      (const __attribute__((address_space(1))) void*)g,
      (__attribute__((address_space(3))) void*)l, 16, 0, 0);
}

// ---- fused pack: fp32 -> bf16 for text [128*64,512] and image padded
// ---- [128,208,512] (pad rows zeroed). 8 elems / thread.
#define TEXT_BLOCKS 2048     // 2048*256*8 = 128*64*512
#define IMG_BLOCKS  6656     // 6656*256*8 = 128*208*512
__global__ void pack_k(const float* __restrict__ img, const float* __restrict__ txt,
                       uint4* __restrict__ imgbf, uint4* __restrict__ txtbf) {
  union { unsigned short s[8]; uint4 q; } u;
  if (blockIdx.x < TEXT_BLOCKS) {
    int c = blockIdx.x * 256 + threadIdx.x;
    const float4* in4 = (const float4*)txt;
    float4 a = in4[2 * c], b = in4[2 * c + 1];
    u.s[0] = f2bf(a.x); u.s[1] = f2bf(a.y); u.s[2] = f2bf(a.z); u.s[3] = f2bf(a.w);
    u.s[4] = f2bf(b.x); u.s[5] = f2bf(b.y); u.s[6] = f2bf(b.z); u.s[7] = f2bf(b.w);
    txtbf[c] = u.q;
  } else {
    int c = (blockIdx.x - TEXT_BLOCKS) * 256 + threadIdx.x;
    int e = c * 8;
    int k = e & (DD - 1);
    int tok = e >> 9;
    int b2 = tok / IP;
    int r = tok - b2 * IP;
    if (r < II) {
      const float4* in4 = (const float4*)(img + ((size_t)(b2 * II + r) * DD + k));
      float4 a = in4[0], b = in4[1];
      u.s[0] = f2bf(a.x); u.s[1] = f2bf(a.y); u.s[2] = f2bf(a.z); u.s[3] = f2bf(a.w);
      u.s[4] = f2bf(b.x); u.s[5] = f2bf(b.y); u.s[6] = f2bf(b.z); u.s[7] = f2bf(b.w);
    } else {
      u.q = make_uint4(0u, 0u, 0u, 0u);
    }
    imgbf[c] = u.q;
  }
}

// ---- main GEMM + fused max/mean ----
// grid: (64 pairs, 128 b2), block: 256 threads (4 waves, 2x2 over M/N)
__global__ __launch_bounds__(256, 2) void maxsim_gemm_k(
    const unsigned short* __restrict__ A,    // text bf16 [128*64, 512]
    const unsigned short* __restrict__ Bm,   // image bf16 [128*208, 512]
    float* __restrict__ sim)                 // [128,128] mean-of-max
{
  // Double-buffered LDS tiles, XOR chunk swizzle:
  // physical chunk p of row r holds logical chunk p ^ ((r>>1)&3)
  __shared__ __align__(16) unsigned short As0[128 * BKK], As1[128 * BKK]; // 8+8 KiB
  __shared__ __align__(16) unsigned short Bs0[IP * BKK],  Bs1[IP * BKK];  // 13+13 KiB
  __shared__ float partial[2][128];

  const int pr  = blockIdx.x;       // text pair: b1 in {2pr, 2pr+1}
  const int b2  = blockIdx.y;
  const int tid = threadIdx.x;
  const int w = tid >> 6, l = tid & 63;
  const int m = l & 15, q = l >> 4;
  const int waveM = w >> 1;
  const int waveN = w & 1;
  const int nt = 7 - waveN;

  // chunk -> 32-bit element offset (saddr + voffset form for global_load_lds)
  const int ca0 = tid, ca1 = tid + 256;
  const int cb0 = tid, cb1 = tid + 256, cb2 = tid + 512, cb3 = 768 + l;
#define AOFF(c) ((unsigned)((pr * 128 + ((c) >> 2)) * DD + ((((c) & 3) ^ ((((c) >> 2) >> 1) & 3)) * 8)))
#define BOFF(c) ((unsigned)((b2 * IP + ((c) >> 2)) * DD + ((((c) & 3) ^ ((((c) >> 2) >> 1) & 3)) * 8)))
  const unsigned oA0 = AOFF(ca0), oA1 = AOFF(ca1);
  const unsigned oB0 = BOFF(cb0), oB1 = BOFF(cb1), oB2 = BOFF(cb2), oB3 = BOFF(cb3);

#define ISSUE(AS, BS, k0) do {                                    \
    async16(A  + oA0 + (k0), (char*)(AS) + ca0 * 16);             \
    async16(A  + oA1 + (k0), (char*)(AS) + ca1 * 16);             \
    async16(Bm + oB0 + (k0), (char*)(BS) + cb0 * 16);             \
    async16(Bm + oB1 + (k0), (char*)(BS) + cb1 * 16);             \
    async16(Bm + oB2 + (k0), (char*)(BS) + cb2 * 16);             \
    if (w == 0) async16(Bm + oB3 + (k0), (char*)(BS) + cb3 * 16); \
  } while (0)

  f4v acc[4][7];
#pragma unroll
  for (int mi = 0; mi < 4; ++mi)
#pragma unroll
    for (int nj = 0; nj < 7; ++nj)
      acc[mi][nj] = (f4v){0.f, 0.f, 0.f, 0.f};

  const int swz = q ^ ((m >> 1) & 3);   // logical chunk q -> physical chunk

#define COMPUTE(AS, BS) do {                                               \
    const s8v* Av = (const s8v*)(AS);                                      \
    const s8v* Bv = (const s8v*)(BS);                                      \
    s8v af[4];                                                             \
    _Pragma("unroll")                                                      \
    for (int mi = 0; mi < 4; ++mi)                                         \
      af[mi] = Av[(waveM * 64 + mi * 16 + m) * 4 + swz];                   \
    _Pragma("unroll")                                                      \
    for (int nj = 0; nj < 7; ++nj) {                                       \
      if (nj < nt) {                                                       \
        s8v bf = Bv[(waveN * 112 + nj * 16 + m) * 4 + swz];                \
        _Pragma("unroll")                                                  \
        for (int mi = 0; mi < 4; ++mi)                                     \
          acc[mi][nj] = __builtin_amdgcn_mfma_f32_16x16x32_bf16(           \
              af[mi], bf, acc[mi][nj], 0, 0, 0);                           \
      }                                                                    \
    }                                                                      \
  } while (0)

  // ---- pipelined K-loop: one barrier per step, prefetch-before-compute ----
  ISSUE(As0, Bs0, 0);
  __syncthreads();                       // cold drain (once)
  for (int ks = 0; ks < KSTEPS; ks += 2) {
    ISSUE(As1, Bs1, (ks + 1) * BKK);     // always valid: ks+1 <= 15
    COMPUTE(As0, Bs0);
    __syncthreads();                     // drains prefetch, hidden by MFMA above
    if (ks + 2 < KSTEPS) ISSUE(As0, Bs0, (ks + 2) * BKK);
    COMPUTE(As1, Bs1);
    __syncthreads();
  }

  // ---- epilogue: max over image cols (mask >=196), then mean over t ----
  // C/D layout (16x16x32): col = lane&15, row = (lane>>4)*4 + reg
  const float NEG = -3.0e38f;
#pragma unroll
  for (int mi = 0; mi < 4; ++mi) {
    float v0 = NEG, v1 = NEG, v2 = NEG, v3 = NEG;
#pragma unroll
    for (int nj = 0; nj < 7; ++nj) {
      if (nj < nt) {
        int col = waveN * 112 + nj * 16 + m;
        bool valid = col < II;
        v0 = fmaxf(v0, valid ? acc[mi][nj][0] : NEG);
        v1 = fmaxf(v1, valid ? acc[mi][nj][1] : NEG);
        v2 = fmaxf(v2, valid ? acc[mi][nj][2] : NEG);
        v3 = fmaxf(v3, valid ? acc[mi][nj][3] : NEG);
      }
    }
#pragma unroll
    for (int off = 1; off < 16; off <<= 1) {
      v0 = fmaxf(v0, __shfl_xor(v0, off));
      v1 = fmaxf(v1, __shfl_xor(v1, off));
      v2 = fmaxf(v2, __shfl_xor(v2, off));
      v3 = fmaxf(v3, __shfl_xor(v3, off));
    }
    if (m == 0) {
      int rowb = waveM * 64 + mi * 16 + q * 4;
      partial[waveN][rowb + 0] = v0;
      partial[waveN][rowb + 1] = v1;
      partial[waveN][rowb + 2] = v2;
      partial[waveN][rowb + 3] = v3;
    }
  }
  __syncthreads();

  if (tid < 128) {
    float v = fmaxf(partial[0][tid], partial[1][tid]);  // max over all 196 i
#pragma unroll
    for (int off = 1; off < 64; off <<= 1) v += __shfl_xor(v, off);
    if ((tid & 63) == 0) {
      int b1 = pr * 2 + (tid >> 6);
      sim[b1 * BB + b2] = v * (1.0f / 64.0f);           // mean over t
    }
  }
}

// ---- symmetric diagonal cross-entropy over the 128x128 sim matrix ----
__global__ void loss_k(const float* __restrict__ sim, float* __restrict__ out) {
  const int b = threadIdx.x;                 // 0..127
  const float sc = 1.0f / 0.07f;
  float rmax = -3.0e38f, cmax = -3.0e38f;
  for (int j = 0; j < BB; ++j) {
    rmax = fmaxf(rmax, sim[b * BB + j]);
    cmax = fmaxf(cmax, sim[j * BB + b]);
  }
  float rs = 0.f, cs = 0.f;
  for (int j = 0; j < BB; ++j) {
    rs += __expf((sim[b * BB + j] - rmax) * sc);
    cs += __expf((sim[j * BB + b] - cmax) * sc);
  }
  float d = sim[b * BB + b];
  float v = (rmax - d) * sc + __logf(rs) + (cmax - d) * sc + __logf(cs);
  __shared__ float red[2];
#pragma unroll
  for (int off = 1; off < 64; off <<= 1) v += __shfl_xor(v, off);
  if ((b & 63) == 0) red[b >> 6] = v;
  __syncthreads();
  if (b == 0) out[0] = (red[0] + red[1]) * 0.5f / 128.0f;
}

extern "C" void kernel_launch(void* const* d_in, const int* in_sizes, int n_in,
                              void* d_out, int out_size, void* d_ws, size_t ws_size,
                              hipStream_t stream) {
  const float* img = (const float*)d_in[0];  // [128,196,512]
  const float* txt = (const float*)d_in[1];  // [128,64,512]
  float* out = (float*)d_out;

  char* ws = (char*)d_ws;
  const size_t TXT_BF = (size_t)BB * TT * DD * 2;        // 8,388,608 B
  const size_t IMG_BF = (size_t)BB * IP * DD * 2;        // 27,262,976 B
  unsigned short* txtbf = (unsigned short*)ws;
  unsigned short* imgbf = (unsigned short*)(ws + TXT_BF);
  float* sim = (float*)(ws + TXT_BF + IMG_BF);           // 65,536 B

  pack_k<<<TEXT_BLOCKS + IMG_BLOCKS, 256, 0, stream>>>(img, txt, (uint4*)imgbf, (uint4*)txtbf);
  maxsim_gemm_k<<<dim3(64, 128), 256, 0, stream>>>(txtbf, imgbf, sim);
  loss_k<<<1, 128, 0, stream>>>(sim, out);
}